// Round 9
// baseline (199.140 us; speedup 1.0000x reference)
//
#include <hip/hip_runtime.h>
#include <stdint.h>

typedef unsigned short u16;
typedef float f32x4 __attribute__((ext_vector_type(4)));
typedef short short8 __attribute__((ext_vector_type(8)));
typedef unsigned uint4v __attribute__((ext_vector_type(4)));

enum { NT = 65536, KC = 2048, D = 128, H = 256, A_DIM = 6 };

__device__ __forceinline__ u16 f2bf(float f) {
    union { float f; unsigned u; } x; x.f = f;
    unsigned r = x.u + 0x7FFFu + ((x.u >> 16) & 1u);
    return (u16)(r >> 16);
}
__device__ __forceinline__ float bf2f(u16 u) {
    union { unsigned u; float f; } x; x.u = ((unsigned)u) << 16;
    return x.f;
}

typedef __attribute__((address_space(1))) void gvoid;
typedef __attribute__((address_space(3))) void lvoid;
__device__ __forceinline__ void gload_lds16(const void* g, void* l) {
    __builtin_amdgcn_global_load_lds((gvoid*)g, (lvoid*)l, 16, 0, 0);
}

// ---------------- prep: transpose+cast weights to bf16 [N][K], cast emb, emb row norms, zero sums
__global__ void prep(const float* __restrict__ W_e2, const float* __restrict__ W_e3,
                     const float* __restrict__ W_d1, const float* __restrict__ W_d2,
                     const float* __restrict__ emb,
                     u16* __restrict__ We2T, u16* __restrict__ We3T,
                     u16* __restrict__ Wd1T, u16* __restrict__ Wd2T,
                     u16* __restrict__ emb_bf, float* __restrict__ norm2,
                     float* __restrict__ sums) {
    int b = blockIdx.x, t = threadIdx.x;
    if (b == 0 && t < 2) sums[t] = 0.f;
    if (b < 256)       { int e = b * 256 + t;          int i = e >> 8, j = e & 255; We2T[j * 256 + i] = f2bf(W_e2[e]); }
    else if (b < 384)  { int e = (b - 256) * 256 + t;  int i = e >> 7, j = e & 127; We3T[j * 256 + i] = f2bf(W_e3[e]); }
    else if (b < 512)  { int e = (b - 384) * 256 + t;  int i = e >> 8, j = e & 255; Wd1T[j * 128 + i] = f2bf(W_d1[e]); }
    else if (b < 768)  { int e = (b - 512) * 256 + t;  int i = e >> 8, j = e & 255; Wd2T[j * 256 + i] = f2bf(W_d2[e]); }
    else if (b < 1792) { int e = (b - 768) * 256 + t;  emb_bf[e] = f2bf(emb[e]); }
    else {
        // emb row squared norms: 512 blocks x 4 waves, one row per wave
        int lane = t & 63, w = t >> 6;
        int r = (b - 1792) * 4 + w;
        float v0 = emb[(size_t)r * D + lane];
        float v1 = emb[(size_t)r * D + 64 + lane];
        float s = v0 * v0 + v1 * v1;
#pragma unroll
        for (int off = 32; off; off >>= 1) s += __shfl_xor(s, off);
        if (lane == 0) norm2[r] = s;
    }
}

// ---------------- encoder layer 1 (K=6): lane = 8 consecutive cols of one row; 16B coalesced stores
__global__ __launch_bounds__(256) void enc1(const float* __restrict__ act, const float* __restrict__ W,
                                            const float* __restrict__ b, u16* __restrict__ h1) {
    const int gid = blockIdx.x * 256 + threadIdx.x;
    const int row = gid >> 5;
    const int col0 = (gid & 31) << 3;
    float x[A_DIM];
#pragma unroll
    for (int i = 0; i < A_DIM; i++) x[i] = act[(size_t)row * A_DIM + i];
    float s[8];
#pragma unroll
    for (int c = 0; c < 8; c++) s[c] = b[col0 + c];
#pragma unroll
    for (int i = 0; i < A_DIM; i++) {
        float xi = x[i];
#pragma unroll
        for (int c = 0; c < 8; c++) s[c] = fmaf(xi, W[i * H + col0 + c], s[c]);
    }
    uint4v o;
#pragma unroll
    for (int c2 = 0; c2 < 4; c2++)
        o[c2] = (unsigned)f2bf(fmaxf(s[c2 * 2], 0.f)) | ((unsigned)f2bf(fmaxf(s[c2 * 2 + 1], 0.f)) << 16);
    *(uint4v*)&h1[(size_t)row * H + col0] = o;
}

// ---------------- bf16 MFMA GEMM: C = act(A[M,K] @ BT[N,K]^T + bias)
// 128x128 tile, BK=64, SINGLE-buffer (32KB LDS -> 5 blocks/CU), XOR-swizzled rows (128B, swz=(row&7)<<4)
template<int RELU>
__global__ __launch_bounds__(256) void gemm_bt(const u16* __restrict__ A, const u16* __restrict__ BT,
                                               const float* __restrict__ bias, u16* __restrict__ C,
                                               int N, int K) {
    __shared__ u16 sA[128 * 64];
    __shared__ u16 sB[128 * 64];
    const int t = threadIdx.x;
    const int lane = t & 63, w = t >> 6, wr = w >> 1, wc = w & 1;
    const int row0 = blockIdx.x * 128, col0 = blockIdx.y * 128;
    f32x4 acc[4][4] = {};
    // staging map: dst byte (p*256+t)*16, row=db>>7 (128B rows), src col inverse-swizzled
    int srow[4], sdst[4], scol[4];
#pragma unroll
    for (int p = 0; p < 4; p++) {
        int db = (p * 256 + t) * 16;
        int row = db >> 7;
        srow[p] = row; sdst[p] = db;
        scol[p] = ((db & 127) ^ ((row & 7) << 4)) >> 1;
    }
    const int ra = wr * 64 + (lane & 15), rb = wc * 64 + (lane & 15);
    const int kbase = (lane >> 4) * 8;
    int aoff[4][2], boff[4][2];
#pragma unroll
    for (int m = 0; m < 4; m++)
#pragma unroll
        for (int ks = 0; ks < 2; ks++) {
            int rA = ra + m * 16, rB = rb + m * 16;
            int kb = (ks * 32 + kbase) << 1;
            aoff[m][ks] = (rA << 7) | (kb ^ ((rA & 7) << 4));
            boff[m][ks] = (rB << 7) | (kb ^ ((rB & 7) << 4));
        }
    const int nsteps = K >> 6;
    for (int s = 0; s < nsteps; s++) {
        if (s) __syncthreads();   // previous step's readers done
        const int k0 = s << 6;
#pragma unroll
        for (int p = 0; p < 4; p++) gload_lds16(A + (size_t)(row0 + srow[p]) * K + k0 + scol[p], (char*)sA + sdst[p]);
#pragma unroll
        for (int p = 0; p < 4; p++) gload_lds16(BT + (size_t)(col0 + srow[p]) * K + k0 + scol[p], (char*)sB + sdst[p]);
        __syncthreads();          // staging complete
#pragma unroll
        for (int ks = 0; ks < 2; ks++) {
            short8 av[4], bv[4];
#pragma unroll
            for (int m = 0; m < 4; m++) av[m] = *(const short8*)((const char*)sA + aoff[m][ks]);
#pragma unroll
            for (int n = 0; n < 4; n++) bv[n] = *(const short8*)((const char*)sB + boff[n][ks]);
#pragma unroll
            for (int m = 0; m < 4; m++)
#pragma unroll
                for (int n = 0; n < 4; n++)
                    acc[m][n] = __builtin_amdgcn_mfma_f32_16x16x32_bf16(av[m], bv[n], acc[m][n], 0, 0, 0);
        }
    }
#pragma unroll
    for (int n = 0; n < 4; n++) {
        int col = col0 + wc * 64 + n * 16 + (lane & 15);
        float bs = bias[col];
#pragma unroll
        for (int m = 0; m < 4; m++) {
            int rbase = row0 + wr * 64 + m * 16 + (lane >> 4) * 4;
#pragma unroll
            for (int j = 0; j < 4; j++) {
                float v = acc[m][n][j] + bs;
                if (RELU) v = fmaxf(v, 0.f);
                C[(size_t)(rbase + j) * N + col] = f2bf(v);
            }
        }
    }
}

// ---------------- distance + argmin + q gather + vq partial
// 64-row tiles -> 1024 blocks -> 4 blocks/CU (16 waves). Each wave owns a 16-code slice
// of each 64-code half-chunk. Ring dbuf + counted vmcnt (R7 rhythm). ~32.3KB LDS.
__global__ __launch_bounds__(256) void vq_dist(const u16* __restrict__ enc_bf, const u16* __restrict__ emb_bf,
                                               const float* __restrict__ emb, const float* __restrict__ norm2,
                                               u16* __restrict__ q_bf, float* __restrict__ sums) {
    __shared__ u16 ring[2][64 * 128];    // 2x16KB; ring[0] transiently holds the 64x128 enc tile
    __shared__ unsigned sKey[64];
    __shared__ float svq[4];
    const int t = threadIdx.x, lane = t & 63, w = t >> 6;
    const int row0 = blockIdx.x * 64;
    // staging map (256B rows, XOR-swizzled source) — used for both enc tile and code half-chunks
    int sbRow[4], sbDst[4], sbCol[4];
#pragma unroll
    for (int p = 0; p < 4; p++) {
        int db = (p * 256 + t) * 16;
        int row = db >> 8;                 // 0..63
        sbRow[p] = row; sbDst[p] = db;
        sbCol[p] = ((db & 255) ^ ((row & 7) << 4)) >> 1;
    }
    // ---- prologue A: stage enc tile (64 rows) into ring[0]
#pragma unroll
    for (int p = 0; p < 4; p++) gload_lds16(enc_bf + (size_t)(row0 + sbRow[p]) * D + sbCol[p], (char*)ring[0] + sbDst[p]);
    const int l15 = lane & 15;
    const int kbase = (lane >> 4) * 8;
    const int rB = w * 16 + l15;               // this wave's code row within the 64-code half-chunk
    int boff[4];
#pragma unroll
    for (int ks = 0; ks < 4; ks++) {
        int kb = (ks * 32 + kbase) << 1;
        boff[ks] = (rB << 8) | (kb ^ ((rB & 7) << 4));
    }
    if (t < 64) sKey[t] = 0xFFFFFFFFu;
    __syncthreads();   // enc tile landed (vmcnt(0) drain, once)
    // ---- hoist A fragments (chunk-invariant): rows m*16+l15, 4 k-slices
    short8 av[4][4];
#pragma unroll
    for (int m = 0; m < 4; m++)
#pragma unroll
        for (int ks = 0; ks < 4; ks++) {
            int rA = m * 16 + l15;
            int kb = (ks * 32 + kbase) << 1;
            av[m][ks] = *(const short8*)((const char*)ring[0] + ((rA << 8) | (kb ^ ((rA & 7) << 4))));
        }
    __syncthreads();   // all waves done reading enc tile; ring[0] reusable
    // ---- prologue B: stage half-chunk 0 into ring[0]
#pragma unroll
    for (int p = 0; p < 4; p++) gload_lds16(emb_bf + (size_t)sbRow[p] * D + sbCol[p], (char*)ring[0] + sbDst[p]);
    unsigned minKey[4][4];
#pragma unroll
    for (int m = 0; m < 4; m++)
#pragma unroll
        for (int j = 0; j < 4; j++) minKey[m][j] = 0xFFFFFFFFu;
    for (int ch = 0; ch < 32; ch++) {
        const int cur = ch & 1;
        // stage next half-chunk; counted wait: own stage(ch) landed, stage(ch+1) stays in flight
        if (ch + 1 < 32) {
            const u16* src = emb_bf + (size_t)(ch + 1) * 64 * D;
#pragma unroll
            for (int p = 0; p < 4; p++) gload_lds16(src + (size_t)sbRow[p] * D + sbCol[p], (char*)ring[cur ^ 1] + sbDst[p]);
            asm volatile("s_waitcnt vmcnt(4)" ::: "memory");
        } else {
            asm volatile("s_waitcnt vmcnt(0)" ::: "memory");
        }
        __builtin_amdgcn_s_barrier();      // all waves' stage(ch) visible
        asm volatile("" ::: "memory");
        const int k = ch * 64 + rB;                       // this lane's code (same for all 16 acc values)
        const float nn = norm2[k] + 1.0f;                 // global, L2-hot; hides under MFMAs
        const unsigned kk = (unsigned)k & 0x7FFu;
        f32x4 acc[4] = {};
#pragma unroll
        for (int ks = 0; ks < 4; ks++) {
            short8 bv = *(const short8*)((const char*)ring[cur] + boff[ks]);
#pragma unroll
            for (int m = 0; m < 4; m++)
                acc[m] = __builtin_amdgcn_mfma_f32_16x16x32_bf16(av[m][ks], bv, acc[m], 0, 0, 0);
        }
#pragma unroll
        for (int m = 0; m < 4; m++)
#pragma unroll
            for (int j = 0; j < 4; j++) {
                float c = fmaf(acc[m][j], -2.f, nn);      // 1 + ||emb||^2 - 2*dot  (>0)
                unsigned key = (__float_as_uint(c) & 0xFFFFF800u) | kk;
                minKey[m][j] = min(minKey[m][j], key);
            }
        asm volatile("" ::: "memory");
        __builtin_amdgcn_s_barrier();      // all waves done reading ring[cur]; safe to overwrite next iter
    }
    // reduce over this wave's 16 codes (lane&15 dimension), then cross-wave via LDS atomicMin
#pragma unroll
    for (int off = 1; off < 16; off <<= 1) {
#pragma unroll
        for (int m = 0; m < 4; m++)
#pragma unroll
            for (int j = 0; j < 4; j++)
                minKey[m][j] = min(minKey[m][j], (unsigned)__shfl_xor((int)minKey[m][j], off));
    }
    if (l15 == 0) {
#pragma unroll
        for (int m = 0; m < 4; m++)
#pragma unroll
            for (int j = 0; j < 4; j++)
                atomicMin(&sKey[m * 16 + (lane >> 4) * 4 + j], minKey[m][j]);
    }
    __syncthreads();
    // gather q (fp32 emb), vq partial vs enc re-read from global (L2-hot); 4-wide batches
    float vql = 0.f;
    for (int g = 0; g < 4; g++) {
        float q0[4], q1[4], e0[4], e1[4];
        int rowv[4];
#pragma unroll
        for (int u = 0; u < 4; u++) {
            int row = w * 16 + g * 4 + u;
            rowv[u] = row;
            int k = (int)(sKey[row] & 0x7FFu);
            q0[u] = emb[(size_t)k * D + lane];
            q1[u] = emb[(size_t)k * D + 64 + lane];
            e0[u] = bf2f(enc_bf[(size_t)(row0 + row) * D + lane]);
            e1[u] = bf2f(enc_bf[(size_t)(row0 + row) * D + 64 + lane]);
        }
#pragma unroll
        for (int u = 0; u < 4; u++) {
            float d0 = q0[u] - e0[u], d1 = q1[u] - e1[u];
            vql += d0 * d0 + d1 * d1;
            q_bf[(size_t)(row0 + rowv[u]) * D + lane] = f2bf(q0[u]);
            q_bf[(size_t)(row0 + rowv[u]) * D + 64 + lane] = f2bf(q1[u]);
        }
    }
#pragma unroll
    for (int off = 32; off; off >>= 1) vql += __shfl_xor(vql, off);
    if (lane == 0) svq[w] = vql;
    __syncthreads();
    if (t == 0) atomicAdd(&sums[0], svq[0] + svq[1] + svq[2] + svq[3]);
}

// ---------------- decoder head: recons = tanh(d2@W_d3+b), accumulate recons MSE
// short8 loads, per-lane W slice in registers, 2 rows/wave, 128 rows/block
__global__ __launch_bounds__(256) void dec3(const u16* __restrict__ d2, const float* __restrict__ W,
                                            const float* __restrict__ b, const float* __restrict__ act,
                                            float* __restrict__ sums) {
    __shared__ float sred[4];
    const int t = threadIdx.x, lane = t & 63, w = t >> 6;
    const int half = lane >> 5, l5 = lane & 31;
    const int col0 = l5 << 3;
    float Wr[8][A_DIM];
#pragma unroll
    for (int c = 0; c < 8; c++)
#pragma unroll
        for (int j = 0; j < A_DIM; j++) Wr[c][j] = W[(col0 + c) * A_DIM + j];
    float rl = 0.f;
    for (int it = 0; it < 16; ++it) {
        const int n = blockIdx.x * 128 + it * 8 + (w << 1) + half;
        short8 v8 = *(const short8*)&d2[(size_t)n * H + col0];
        float p[A_DIM] = {};
#pragma unroll
        for (int c = 0; c < 8; c++) {
            float v = bf2f((u16)v8[c]);
#pragma unroll
            for (int j = 0; j < A_DIM; j++) p[j] = fmaf(v, Wr[c][j], p[j]);
        }
#pragma unroll
        for (int j = 0; j < A_DIM; j++)
#pragma unroll
            for (int off = 16; off; off >>= 1) p[j] += __shfl_xor(p[j], off);
        if (l5 == 0) {
            float s = 0.f;
#pragma unroll
            for (int j = 0; j < A_DIM; j++) {
                float r = tanhf(p[j] + b[j]);
                float df = r - act[(size_t)n * A_DIM + j];
                s += df * df;
            }
            rl += s;
        }
    }
    rl += __shfl_xor(rl, 32);
    if (lane == 0) sred[w] = rl;
    __syncthreads();
    if (t == 0) atomicAdd(&sums[1], sred[0] + sred[1] + sred[2] + sred[3]);
}

// ---------------- OUTPUT IS FLOAT32 ----------------
__global__ void finalize(const float* __restrict__ sums, float* __restrict__ out) {
    if (threadIdx.x == 0) {
        float vq = 1.25f * sums[0] / (float)(NT * D);
        float rec = sums[1] / (float)(NT * A_DIM);
        out[0] = rec + vq;
        out[1] = rec;
        out[2] = vq;
    }
}

extern "C" void kernel_launch(void* const* d_in, const int* in_sizes, int n_in,
                              void* d_out, int out_size, void* d_ws, size_t ws_size,
                              hipStream_t stream) {
    const float* action = (const float*)d_in[0];
    const float* W_e1 = (const float*)d_in[1];
    const float* b_e1 = (const float*)d_in[2];
    const float* W_e2 = (const float*)d_in[3];
    const float* b_e2 = (const float*)d_in[4];
    const float* W_e3 = (const float*)d_in[5];
    const float* b_e3 = (const float*)d_in[6];
    const float* emb  = (const float*)d_in[7];
    const float* W_d1 = (const float*)d_in[8];
    const float* b_d1 = (const float*)d_in[9];
    const float* W_d2 = (const float*)d_in[10];
    const float* b_d2 = (const float*)d_in[11];
    const float* W_d3 = (const float*)d_in[12];
    const float* b_d3 = (const float*)d_in[13];

    char* ws = (char*)d_ws;
    float* sums  = (float*)ws;                  // 256 B  [0]=vq_sum [1]=rec_sum
    float* norm2 = (float*)(ws + 256);          // 8 KB
    u16* We2T   = (u16*)(ws + 8448);            // 128 KB  [256][256]
    u16* We3T   = (u16*)(ws + 139520);          // 64 KB   [128][256]
    u16* Wd1T   = (u16*)(ws + 205056);          // 64 KB   [256][128]
    u16* Wd2T   = (u16*)(ws + 270592);          // 128 KB  [256][256]
    u16* emb_bf = (u16*)(ws + 401664);          // 512 KB  [2048][128]
    u16* h1     = (u16*)(ws + 925952);          // 32 MB   [NT][256]
    u16* h2     = (u16*)(ws + 925952 + 33554432);        // 32 MB
    u16* encb   = (u16*)(ws + 925952 + 67108864);        // 16 MB [NT][128]
    u16* qb     = (u16*)(ws + 925952 + 83886080);        // 16 MB [NT][128]
    u16* d1 = h1;   // h1 dead after encoder GEMM2
    u16* d2 = h2;   // h2 dead after enc GEMM3

    prep<<<2304, 256, 0, stream>>>(W_e2, W_e3, W_d1, W_d2, emb, We2T, We3T, Wd1T, Wd2T, emb_bf, norm2, sums);
    enc1<<<NT * 32 / 256, 256, 0, stream>>>(action, W_e1, b_e1, h1);
    gemm_bt<1><<<dim3(NT / 128, 2), 256, 0, stream>>>(h1, We2T, b_e2, h2, H, H);
    gemm_bt<0><<<dim3(NT / 128, 1), 256, 0, stream>>>(h2, We3T, b_e3, encb, D, H);
    vq_dist<<<NT / 64, 256, 0, stream>>>(encb, emb_bf, emb, norm2, qb, sums);
    gemm_bt<1><<<dim3(NT / 128, 2), 256, 0, stream>>>(qb, Wd1T, b_d1, d1, H, D);
    gemm_bt<1><<<dim3(NT / 128, 2), 256, 0, stream>>>(d1, Wd2T, b_d2, d2, H, H);
    dec3<<<NT / 128, 256, 0, stream>>>(d2, W_d3, b_d3, action, sums);
    finalize<<<1, 64, 0, stream>>>(sums, (float*)d_out);
}

// Round 10
// 167.186 us; speedup vs baseline: 1.1911x; 1.1911x over previous
//
#include <hip/hip_runtime.h>
#include <stdint.h>

typedef unsigned short u16;
typedef float f32x4 __attribute__((ext_vector_type(4)));
typedef short short8 __attribute__((ext_vector_type(8)));
typedef unsigned uint4v __attribute__((ext_vector_type(4)));

enum { NT = 65536, KC = 2048, D = 128, H = 256, A_DIM = 6 };

__device__ __forceinline__ u16 f2bf(float f) {
    union { float f; unsigned u; } x; x.f = f;
    unsigned r = x.u + 0x7FFFu + ((x.u >> 16) & 1u);
    return (u16)(r >> 16);
}
__device__ __forceinline__ float bf2f(u16 u) {
    union { unsigned u; float f; } x; x.u = ((unsigned)u) << 16;
    return x.f;
}

typedef __attribute__((address_space(1))) void gvoid;
typedef __attribute__((address_space(3))) void lvoid;
__device__ __forceinline__ void gload_lds16(const void* g, void* l) {
    __builtin_amdgcn_global_load_lds((gvoid*)g, (lvoid*)l, 16, 0, 0);
}

// ---------------- prep: transpose+cast weights to bf16 [N][K], cast emb, emb row norms, zero sums
__global__ void prep(const float* __restrict__ W_e2, const float* __restrict__ W_e3,
                     const float* __restrict__ W_d1, const float* __restrict__ W_d2,
                     const float* __restrict__ emb,
                     u16* __restrict__ We2T, u16* __restrict__ We3T,
                     u16* __restrict__ Wd1T, u16* __restrict__ Wd2T,
                     u16* __restrict__ emb_bf, float* __restrict__ norm2,
                     float* __restrict__ sums) {
    int b = blockIdx.x, t = threadIdx.x;
    if (b == 0 && t < 2) sums[t] = 0.f;
    if (b < 256)       { int e = b * 256 + t;          int i = e >> 8, j = e & 255; We2T[j * 256 + i] = f2bf(W_e2[e]); }
    else if (b < 384)  { int e = (b - 256) * 256 + t;  int i = e >> 7, j = e & 127; We3T[j * 256 + i] = f2bf(W_e3[e]); }
    else if (b < 512)  { int e = (b - 384) * 256 + t;  int i = e >> 8, j = e & 255; Wd1T[j * 128 + i] = f2bf(W_d1[e]); }
    else if (b < 768)  { int e = (b - 512) * 256 + t;  int i = e >> 8, j = e & 255; Wd2T[j * 256 + i] = f2bf(W_d2[e]); }
    else if (b < 1792) { int e = (b - 768) * 256 + t;  emb_bf[e] = f2bf(emb[e]); }
    else {
        // emb row squared norms: 512 blocks x 4 waves, one row per wave
        int lane = t & 63, w = t >> 6;
        int r = (b - 1792) * 4 + w;
        float v0 = emb[(size_t)r * D + lane];
        float v1 = emb[(size_t)r * D + 64 + lane];
        float s = v0 * v0 + v1 * v1;
#pragma unroll
        for (int off = 32; off; off >>= 1) s += __shfl_xor(s, off);
        if (lane == 0) norm2[r] = s;
    }
}

// ---------------- encoder layer 1 (K=6): lane = 8 consecutive cols of one row; 16B coalesced stores
__global__ __launch_bounds__(256) void enc1(const float* __restrict__ act, const float* __restrict__ W,
                                            const float* __restrict__ b, u16* __restrict__ h1) {
    const int gid = blockIdx.x * 256 + threadIdx.x;
    const int row = gid >> 5;
    const int col0 = (gid & 31) << 3;
    float x[A_DIM];
#pragma unroll
    for (int i = 0; i < A_DIM; i++) x[i] = act[(size_t)row * A_DIM + i];
    float s[8];
#pragma unroll
    for (int c = 0; c < 8; c++) s[c] = b[col0 + c];
#pragma unroll
    for (int i = 0; i < A_DIM; i++) {
        float xi = x[i];
#pragma unroll
        for (int c = 0; c < 8; c++) s[c] = fmaf(xi, W[i * H + col0 + c], s[c]);
    }
    uint4v o;
#pragma unroll
    for (int c2 = 0; c2 < 4; c2++)
        o[c2] = (unsigned)f2bf(fmaxf(s[c2 * 2], 0.f)) | ((unsigned)f2bf(fmaxf(s[c2 * 2 + 1], 0.f)) << 16);
    *(uint4v*)&h1[(size_t)row * H + col0] = o;
}

// ---------------- bf16 MFMA GEMM: C = act(A[M,K] @ BT[N,K]^T + bias)
// 128x128 tile, BK=64, SINGLE-buffer (32KB LDS -> 5 blocks/CU), XOR-swizzled rows (128B, swz=(row&7)<<4)
template<int RELU>
__global__ __launch_bounds__(256) void gemm_bt(const u16* __restrict__ A, const u16* __restrict__ BT,
                                               const float* __restrict__ bias, u16* __restrict__ C,
                                               int N, int K) {
    __shared__ u16 sA[128 * 64];
    __shared__ u16 sB[128 * 64];
    const int t = threadIdx.x;
    const int lane = t & 63, w = t >> 6, wr = w >> 1, wc = w & 1;
    const int row0 = blockIdx.x * 128, col0 = blockIdx.y * 128;
    f32x4 acc[4][4] = {};
    int srow[4], sdst[4], scol[4];
#pragma unroll
    for (int p = 0; p < 4; p++) {
        int db = (p * 256 + t) * 16;
        int row = db >> 7;
        srow[p] = row; sdst[p] = db;
        scol[p] = ((db & 127) ^ ((row & 7) << 4)) >> 1;
    }
    const int ra = wr * 64 + (lane & 15), rb = wc * 64 + (lane & 15);
    const int kbase = (lane >> 4) * 8;
    int aoff[4][2], boff[4][2];
#pragma unroll
    for (int m = 0; m < 4; m++)
#pragma unroll
        for (int ks = 0; ks < 2; ks++) {
            int rA = ra + m * 16, rB = rb + m * 16;
            int kb = (ks * 32 + kbase) << 1;
            aoff[m][ks] = (rA << 7) | (kb ^ ((rA & 7) << 4));
            boff[m][ks] = (rB << 7) | (kb ^ ((rB & 7) << 4));
        }
    const int nsteps = K >> 6;
    for (int s = 0; s < nsteps; s++) {
        if (s) __syncthreads();
        const int k0 = s << 6;
#pragma unroll
        for (int p = 0; p < 4; p++) gload_lds16(A + (size_t)(row0 + srow[p]) * K + k0 + scol[p], (char*)sA + sdst[p]);
#pragma unroll
        for (int p = 0; p < 4; p++) gload_lds16(BT + (size_t)(col0 + srow[p]) * K + k0 + scol[p], (char*)sB + sdst[p]);
        __syncthreads();
#pragma unroll
        for (int ks = 0; ks < 2; ks++) {
            short8 av[4], bv[4];
#pragma unroll
            for (int m = 0; m < 4; m++) av[m] = *(const short8*)((const char*)sA + aoff[m][ks]);
#pragma unroll
            for (int n = 0; n < 4; n++) bv[n] = *(const short8*)((const char*)sB + boff[n][ks]);
#pragma unroll
            for (int m = 0; m < 4; m++)
#pragma unroll
                for (int n = 0; n < 4; n++)
                    acc[m][n] = __builtin_amdgcn_mfma_f32_16x16x32_bf16(av[m], bv[n], acc[m][n], 0, 0, 0);
        }
    }
#pragma unroll
    for (int n = 0; n < 4; n++) {
        int col = col0 + wc * 64 + n * 16 + (lane & 15);
        float bs = bias[col];
#pragma unroll
        for (int m = 0; m < 4; m++) {
            int rbase = row0 + wr * 64 + m * 16 + (lane >> 4) * 4;
#pragma unroll
            for (int j = 0; j < 4; j++) {
                float v = acc[m][n][j] + bs;
                if (RELU) v = fmaxf(v, 0.f);
                C[(size_t)(rbase + j) * N + col] = f2bf(v);
            }
        }
    }
}

// ---------------- final GEMM + decoder-head fusion:
// d2 = relu(d1 @ Wd2T^T + b_d2) contracted in-register against W_d3[256][6];
// writes per-row fp32 partials part[slab=by*2+wc][row][6]; d2 never materialized.
__global__ __launch_bounds__(256) void gemm_head(const u16* __restrict__ A, const u16* __restrict__ BT,
                                                 const float* __restrict__ bias, const float* __restrict__ W3,
                                                 float* __restrict__ part) {
    __shared__ u16 sA[128 * 64];
    __shared__ u16 sB[128 * 64];
    const int t = threadIdx.x;
    const int lane = t & 63, w = t >> 6, wr = w >> 1, wc = w & 1;
    const int row0 = blockIdx.x * 128, col0 = blockIdx.y * 128;
    const int K = H, Ncols = H;
    f32x4 acc[4][4] = {};
    int srow[4], sdst[4], scol[4];
#pragma unroll
    for (int p = 0; p < 4; p++) {
        int db = (p * 256 + t) * 16;
        int row = db >> 7;
        srow[p] = row; sdst[p] = db;
        scol[p] = ((db & 127) ^ ((row & 7) << 4)) >> 1;
    }
    const int ra = wr * 64 + (lane & 15), rb = wc * 64 + (lane & 15);
    const int kbase = (lane >> 4) * 8;
    int aoff[4][2], boff[4][2];
#pragma unroll
    for (int m = 0; m < 4; m++)
#pragma unroll
        for (int ks = 0; ks < 2; ks++) {
            int rA = ra + m * 16, rB = rb + m * 16;
            int kb = (ks * 32 + kbase) << 1;
            aoff[m][ks] = (rA << 7) | (kb ^ ((rA & 7) << 4));
            boff[m][ks] = (rB << 7) | (kb ^ ((rB & 7) << 4));
        }
    const int nsteps = K >> 6;
    for (int s = 0; s < nsteps; s++) {
        if (s) __syncthreads();
        const int k0 = s << 6;
#pragma unroll
        for (int p = 0; p < 4; p++) gload_lds16(A + (size_t)(row0 + srow[p]) * K + k0 + scol[p], (char*)sA + sdst[p]);
#pragma unroll
        for (int p = 0; p < 4; p++) gload_lds16(BT + (size_t)(col0 + srow[p]) * K + k0 + scol[p], (char*)sB + sdst[p]);
        __syncthreads();
#pragma unroll
        for (int ks = 0; ks < 2; ks++) {
            short8 av[4], bv[4];
#pragma unroll
            for (int m = 0; m < 4; m++) av[m] = *(const short8*)((const char*)sA + aoff[m][ks]);
#pragma unroll
            for (int n = 0; n < 4; n++) bv[n] = *(const short8*)((const char*)sB + boff[n][ks]);
#pragma unroll
            for (int m = 0; m < 4; m++)
#pragma unroll
                for (int n = 0; n < 4; n++)
                    acc[m][n] = __builtin_amdgcn_mfma_f32_16x16x32_bf16(av[m], bv[n], acc[m][n], 0, 0, 0);
        }
    }
    // ---- fused head epilogue (loads after K-loop to keep loop VGPR low)
    const int l15 = lane & 15;
    float bs[4], W3r[4][A_DIM];
#pragma unroll
    for (int n = 0; n < 4; n++) {
        int col = col0 + wc * 64 + n * 16 + l15;
        bs[n] = bias[col];
#pragma unroll
        for (int j = 0; j < A_DIM; j++) W3r[n][j] = W3[col * A_DIM + j];
    }
    const int slab = blockIdx.y * 2 + wc;
    float* ps = part + (size_t)slab * NT * A_DIM;
#pragma unroll
    for (int m = 0; m < 4; m++) {
#pragma unroll
        for (int j = 0; j < 4; j++) {
            int row = row0 + wr * 64 + m * 16 + (lane >> 4) * 4 + j;
            float p[A_DIM] = {};
#pragma unroll
            for (int n = 0; n < 4; n++) {
                float v = fmaxf(acc[m][n][j] + bs[n], 0.f);
#pragma unroll
                for (int jj = 0; jj < A_DIM; jj++) p[jj] = fmaf(v, W3r[n][jj], p[jj]);
            }
#pragma unroll
            for (int off = 1; off < 16; off <<= 1)
#pragma unroll
                for (int jj = 0; jj < A_DIM; jj++) p[jj] += __shfl_xor(p[jj], off);
            if (l15 == 0) {
#pragma unroll
                for (int jj = 0; jj < A_DIM; jj++) ps[(size_t)row * A_DIM + jj] = p[jj];
            }
        }
    }
}

// ---------------- head finalize: recons = tanh(sum of 4 partials + b3), MSE accumulate
__global__ __launch_bounds__(256) void head_final(const float* __restrict__ part, const float* __restrict__ b3,
                                                  const float* __restrict__ act, float* __restrict__ sums) {
    __shared__ float sred[4];
    const int t = threadIdx.x, lane = t & 63, w = t >> 6;
    const int n = blockIdx.x * 256 + t;
    float s = 0.f;
#pragma unroll
    for (int j = 0; j < A_DIM; j++) {
        float v = b3[j];
#pragma unroll
        for (int sl = 0; sl < 4; sl++) v += part[(size_t)sl * NT * A_DIM + (size_t)n * A_DIM + j];
        float r = tanhf(v);
        float df = r - act[(size_t)n * A_DIM + j];
        s += df * df;
    }
#pragma unroll
    for (int off = 32; off; off >>= 1) s += __shfl_xor(s, off);
    if (lane == 0) sred[w] = s;
    __syncthreads();
    if (t == 0) atomicAdd(&sums[1], sred[0] + sred[1] + sred[2] + sred[3]);
}

// ---------------- distance + argmin + q gather + vq partial (R5 structure: best measured 56.5us)
__global__ __launch_bounds__(256) void vq_dist(const u16* __restrict__ enc_bf, const u16* __restrict__ emb_bf,
                                               const float* __restrict__ emb, const float* __restrict__ norm2,
                                               u16* __restrict__ q_bf, float* __restrict__ sums) {
    __shared__ u16 sA[128 * 128];
    __shared__ u16 sB[128 * 128];
    __shared__ float sN[KC];
    __shared__ unsigned sKey[128];
    __shared__ float svq[4];
    const int t = threadIdx.x, lane = t & 63, w = t >> 6, wr = w >> 1, wc = w & 1;
    const int row0 = blockIdx.x * 128;
    int srow[8], sdst[8], scol[8];
#pragma unroll
    for (int p = 0; p < 8; p++) {
        int db = (p * 256 + t) * 16;
        int row = db >> 8;
        srow[p] = row; sdst[p] = db;
        scol[p] = ((db & 255) ^ ((row & 7) << 4)) >> 1;
    }
#pragma unroll
    for (int p = 0; p < 8; p++) gload_lds16(enc_bf + (size_t)(row0 + srow[p]) * D + scol[p], (char*)sA + sdst[p]);
#pragma unroll
    for (int p = 0; p < 8; p++) gload_lds16(emb_bf + (size_t)srow[p] * D + scol[p], (char*)sB + sdst[p]);
    for (int i = t; i < KC; i += 256) sN[i] = norm2[i] + 1.0f;
    const int ra = wr * 64 + (lane & 15), rb = wc * 64 + (lane & 15);
    const int kbase = (lane >> 4) * 8;
    int boff[4][4];
#pragma unroll
    for (int m = 0; m < 4; m++)
#pragma unroll
        for (int ks = 0; ks < 4; ks++) {
            int rB = rb + m * 16;
            int kb = (ks * 32 + kbase) << 1;
            boff[m][ks] = (rB << 8) | (kb ^ ((rB & 7) << 4));
        }
    __syncthreads();
    short8 av[4][4];
#pragma unroll
    for (int m = 0; m < 4; m++)
#pragma unroll
        for (int ks = 0; ks < 4; ks++) {
            int rA = ra + m * 16;
            int kb = (ks * 32 + kbase) << 1;
            av[m][ks] = *(const short8*)((const char*)sA + ((rA << 8) | (kb ^ ((rA & 7) << 4))));
        }
    unsigned minKey[4][4];
#pragma unroll
    for (int m = 0; m < 4; m++)
#pragma unroll
        for (int j = 0; j < 4; j++) minKey[m][j] = 0xFFFFFFFFu;
    for (int ch = 0; ch < 16; ch++) {
        if (ch) {
            __syncthreads();
            const u16* src = emb_bf + (size_t)ch * 128 * D;
#pragma unroll
            for (int p = 0; p < 8; p++) gload_lds16(src + (size_t)srow[p] * D + scol[p], (char*)sB + sdst[p]);
            __syncthreads();
        }
        f32x4 acc[4][4] = {};
#pragma unroll
        for (int ks = 0; ks < 4; ks++) {
            short8 bv[4];
#pragma unroll
            for (int n = 0; n < 4; n++) bv[n] = *(const short8*)((const char*)sB + boff[n][ks]);
#pragma unroll
            for (int m = 0; m < 4; m++)
#pragma unroll
                for (int n = 0; n < 4; n++)
                    acc[m][n] = __builtin_amdgcn_mfma_f32_16x16x32_bf16(av[m][ks], bv[n], acc[m][n], 0, 0, 0);
        }
#pragma unroll
        for (int n = 0; n < 4; n++) {
            int k = ch * 128 + rb + n * 16;
            float nn = sN[k];
#pragma unroll
            for (int m = 0; m < 4; m++)
#pragma unroll
                for (int j = 0; j < 4; j++) {
                    float c = fmaf(acc[m][n][j], -2.f, nn);
                    unsigned key = (__float_as_uint(c) & 0xFFFFF800u) | (unsigned)k;
                    minKey[m][j] = min(minKey[m][j], key);
                }
        }
    }
#pragma unroll
    for (int off = 1; off < 16; off <<= 1) {
#pragma unroll
        for (int m = 0; m < 4; m++)
#pragma unroll
            for (int j = 0; j < 4; j++)
                minKey[m][j] = min(minKey[m][j], (unsigned)__shfl_xor((int)minKey[m][j], off));
    }
    __syncthreads();
    if (wc == 0 && (lane & 15) == 0) {
#pragma unroll
        for (int m = 0; m < 4; m++)
#pragma unroll
            for (int j = 0; j < 4; j++) {
                int row = wr * 64 + m * 16 + (lane >> 4) * 4 + j;
                sKey[row] = minKey[m][j];
            }
    }
    __syncthreads();
    if (wc == 1 && (lane & 15) == 0) {
#pragma unroll
        for (int m = 0; m < 4; m++)
#pragma unroll
            for (int j = 0; j < 4; j++) {
                int row = wr * 64 + m * 16 + (lane >> 4) * 4 + j;
                if (minKey[m][j] < sKey[row]) sKey[row] = minKey[m][j];
            }
    }
    __syncthreads();
    float vql = 0.f;
    for (int rr = 0; rr < 32; rr++) {
        int row = w * 32 + rr;
        int k = (int)(sKey[row] & 0x7FFu);
        float q0 = emb[(size_t)k * D + lane];
        float q1 = emb[(size_t)k * D + 64 + lane];
        int swz = (row & 7) << 4;
        float e0 = bf2f(*(const u16*)((const char*)sA + ((row << 8) | ((lane << 1) ^ swz))));
        float e1 = bf2f(*(const u16*)((const char*)sA + ((row << 8) | (((lane + 64) << 1) ^ swz))));
        float d0 = q0 - e0, d1 = q1 - e1;
        vql += d0 * d0 + d1 * d1;
        q_bf[(size_t)(row0 + row) * D + lane] = f2bf(q0);
        q_bf[(size_t)(row0 + row) * D + 64 + lane] = f2bf(q1);
    }
#pragma unroll
    for (int off = 32; off; off >>= 1) vql += __shfl_xor(vql, off);
    if (lane == 0) svq[w] = vql;
    __syncthreads();
    if (t == 0) atomicAdd(&sums[0], svq[0] + svq[1] + svq[2] + svq[3]);
}

// ---------------- OUTPUT IS FLOAT32 ----------------
__global__ void finalize(const float* __restrict__ sums, float* __restrict__ out) {
    if (threadIdx.x == 0) {
        float vq = 1.25f * sums[0] / (float)(NT * D);
        float rec = sums[1] / (float)(NT * A_DIM);
        out[0] = rec + vq;
        out[1] = rec;
        out[2] = vq;
    }
}

extern "C" void kernel_launch(void* const* d_in, const int* in_sizes, int n_in,
                              void* d_out, int out_size, void* d_ws, size_t ws_size,
                              hipStream_t stream) {
    const float* action = (const float*)d_in[0];
    const float* W_e1 = (const float*)d_in[1];
    const float* b_e1 = (const float*)d_in[2];
    const float* W_e2 = (const float*)d_in[3];
    const float* b_e2 = (const float*)d_in[4];
    const float* W_e3 = (const float*)d_in[5];
    const float* b_e3 = (const float*)d_in[6];
    const float* emb  = (const float*)d_in[7];
    const float* W_d1 = (const float*)d_in[8];
    const float* b_d1 = (const float*)d_in[9];
    const float* W_d2 = (const float*)d_in[10];
    const float* b_d2 = (const float*)d_in[11];
    const float* W_d3 = (const float*)d_in[12];
    const float* b_d3 = (const float*)d_in[13];

    char* ws = (char*)d_ws;
    float* sums  = (float*)ws;                  // 256 B  [0]=vq_sum [1]=rec_sum
    float* norm2 = (float*)(ws + 256);          // 8 KB
    u16* We2T   = (u16*)(ws + 8448);            // 128 KB  [256][256]
    u16* We3T   = (u16*)(ws + 139520);          // 64 KB   [128][256]
    u16* Wd1T   = (u16*)(ws + 205056);          // 64 KB   [256][128]
    u16* Wd2T   = (u16*)(ws + 270592);          // 128 KB  [256][256]
    u16* emb_bf = (u16*)(ws + 401664);          // 512 KB  [2048][128]
    u16* h1     = (u16*)(ws + 925952);          // 32 MB   [NT][256]
    u16* h2     = (u16*)(ws + 925952 + 33554432);        // 32 MB
    u16* encb   = (u16*)(ws + 925952 + 67108864);        // 16 MB [NT][128]
    u16* qb     = (u16*)(ws + 925952 + 83886080);        // 16 MB [NT][128]
    u16* d1 = h1;                 // h1 dead after encoder GEMM2
    float* part = (float*)h2;     // h2 dead after enc GEMM3; 4 x [NT][6] fp32 = 6.3 MB

    prep<<<2304, 256, 0, stream>>>(W_e2, W_e3, W_d1, W_d2, emb, We2T, We3T, Wd1T, Wd2T, emb_bf, norm2, sums);
    enc1<<<NT * 32 / 256, 256, 0, stream>>>(action, W_e1, b_e1, h1);
    gemm_bt<1><<<dim3(NT / 128, 2), 256, 0, stream>>>(h1, We2T, b_e2, h2, H, H);
    gemm_bt<0><<<dim3(NT / 128, 1), 256, 0, stream>>>(h2, We3T, b_e3, encb, D, H);
    vq_dist<<<NT / 128, 256, 0, stream>>>(encb, emb_bf, emb, norm2, qb, sums);
    gemm_bt<1><<<dim3(NT / 128, 2), 256, 0, stream>>>(qb, Wd1T, b_d1, d1, H, D);
    gemm_head<<<dim3(NT / 128, 2), 256, 0, stream>>>(d1, Wd2T, b_d2, W_d3, part);
    head_final<<<NT / 256, 256, 0, stream>>>(part, b_d3, action, sums);
    finalize<<<1, 64, 0, stream>>>(sums, (float*)d_out);
}